// Round 1
// 92.076 us; speedup vs baseline: 1.1760x; 1.1760x over previous
//
#include <hip/hip_runtime.h>
#include <math.h>

#define NG 9
#define NBLK 1024           // persistent pair blocks: 4/CU on 256 CUs
#define JT 16               // j-tile held in LDS
#define LOG2E 1.4426950408889634f
#define LN2   0.6931471805599453f

// ---------------------------------------------------------------------------
// Kernel 1: classify once, compact toxic -> iLM, non-toxic -> jLM (global),
// and accumulate all counts. Logits stored pre-scaled by log2(e) so the pair
// kernel can run softplus in log2 domain (defer *ln2 to finalize).
// cnts layout (ints): [0]=nI(=nT), [1]=nJ(=nN), [2..10]=cT[g], [11..19]=cN[g]
// ---------------------------------------------------------------------------
__global__ __launch_bounds__(256) void k_classify(
    const float* __restrict__ logits, const float* __restrict__ ytox,
    const float* __restrict__ yid, int B, int* __restrict__ cnts,
    float2* __restrict__ iLM, float2* __restrict__ jLM) {

    __shared__ int wT[4], wN[4], offT[4], offN[4], bT, bN;
    __shared__ int gT[4][NG], gN[4][NG];

    const int tid = threadIdx.x, lane = tid & 63, wave = tid >> 6;
    const int row = blockIdx.x * 256 + tid;
    const bool v = row < B;

    float l = 0.f; bool tox = false, non = false; int m = 0;
    if (v) {
        l = logits[row] * LOG2E;
        tox = ytox[row] >= 0.5f;
        non = !tox;
#pragma unroll
        for (int g = 0; g < NG; ++g)
            if (yid[row * NG + g] >= 0.5f) m |= 1 << g;
    }

    const unsigned long long bTox = __ballot(tox), bNon = __ballot(non);
    const unsigned long long lt = (1ull << lane) - 1ull;
    const int pT = __popcll(bTox & lt), pN = __popcll(bNon & lt);
    if (lane == 0) { wT[wave] = __popcll(bTox); wN[wave] = __popcll(bNon); }
#pragma unroll
    for (int g = 0; g < NG; ++g) {
        const unsigned long long bt = __ballot(tox && ((m >> g) & 1));
        const unsigned long long bn = __ballot(non && ((m >> g) & 1));
        if (lane == 0) { gT[wave][g] = __popcll(bt); gN[wave][g] = __popcll(bn); }
    }
    __syncthreads();
    if (tid == 0) {
        int a = 0, b = 0;
#pragma unroll
        for (int w = 0; w < 4; ++w) { offT[w] = a; a += wT[w]; offN[w] = b; b += wN[w]; }
        bT = atomicAdd(&cnts[0], a);
        bN = atomicAdd(&cnts[1], b);
    }
    __syncthreads();
    if (tox) iLM[bT + offT[wave] + pT] = make_float2(l, __int_as_float(m));
    if (non) jLM[bN + offN[wave] + pN] = make_float2(l, __int_as_float(m));
    if (tid < NG)
        atomicAdd(&cnts[2 + tid], gT[0][tid] + gT[1][tid] + gT[2][tid] + gT[3][tid]);
    else if (tid < 2 * NG) {
        const int g = tid - NG;
        atomicAdd(&cnts[11 + g], gN[0][g] + gN[1][g] + gN[2][g] + gN[3][g]);
    }
}

// ---------------------------------------------------------------------------
// Kernel 2: persistent pair kernel over the compacted lists.
// i-tiles of 512 (IB=2 per thread, exact), j-tiles of JT in LDS.
// j-major tile enumeration => a block's i-fragment (and its 20 accumulators)
// persists across tiles; the 27-value shfl fold runs once per i-fragment.
// Invalid i slots get li=+1e30 -> exp2(-inf)=0 -> log(1)=0: contributes 0.
// ---------------------------------------------------------------------------
__global__ __launch_bounds__(256, 4) void k_pairs(
    const int* __restrict__ cnts, const float2* __restrict__ iLM,
    const float2* __restrict__ jLM, float* __restrict__ part) {

    __shared__ float2 jS[JT];
    __shared__ float red[4][27];
    __shared__ float acc[27];

    const int tid = threadIdx.x, lane = tid & 63, wave = tid >> 6;
    const int blk = blockIdx.x;
    const int nI = cnts[0], nJ = cnts[1];
    const int nbI = (nI + 511) >> 9;
    const int nbJ = (nJ + JT - 1) / JT;
    const int nT = nbI * nbJ;

    if (tid < 27) acc[tid] = 0.f;

    float li0 = 1e30f, li1 = 1e30f;
    int mi0 = 0, mi1 = 0;
    float Ra0 = 0.f, Ra1 = 0.f;
    float Rg0[NG], Rg1[NG];
#pragma unroll
    for (int g = 0; g < NG; ++g) { Rg0[g] = 0.f; Rg1[g] = 0.f; }

    auto flush = [&]() {   // fold 2 i-slots x 9 groups into 27 block sums
#pragma unroll
        for (int g = 0; g < NG; ++g) {
            const bool i0 = (mi0 >> g) & 1, i1 = (mi1 >> g) & 1;
            float x0 = (i0 ? Rg0[g] : 0.f) + (i1 ? Rg1[g] : 0.f);
            float x1 = (i0 ? 0.f : Rg0[g]) + (i1 ? 0.f : Rg1[g]);
            float x2 = (i0 ? (Ra0 - Rg0[g]) : 0.f) + (i1 ? (Ra1 - Rg1[g]) : 0.f);
#pragma unroll
            for (int off = 32; off > 0; off >>= 1) {
                x0 += __shfl_xor(x0, off, 64);
                x1 += __shfl_xor(x1, off, 64);
                x2 += __shfl_xor(x2, off, 64);
            }
            if (lane == 0) {
                red[wave][g] = x0; red[wave][NG + g] = x1; red[wave][2 * NG + g] = x2;
            }
        }
        __syncthreads();
        if (tid < 27)
            acc[tid] += red[0][tid] + red[1][tid] + red[2][tid] + red[3][tid];
    };

    int prev_bi = -1;
    for (int t = blk; t < nT; t += NBLK) {
        const int bi = t % nbI, bj = t / nbI;   // j-major: bi stable per block
        if (bi != prev_bi) {
            if (prev_bi >= 0) flush();
            const int k0 = (bi << 9) + tid, k1 = k0 + 256;
            const float2 a0 = (k0 < nI) ? iLM[k0] : make_float2(1e30f, 0.f);
            const float2 a1 = (k1 < nI) ? iLM[k1] : make_float2(1e30f, 0.f);
            li0 = a0.x; mi0 = __float_as_int(a0.y);
            li1 = a1.x; mi1 = __float_as_int(a1.y);
            Ra0 = 0.f; Ra1 = 0.f;
#pragma unroll
            for (int g = 0; g < NG; ++g) { Rg0[g] = 0.f; Rg1[g] = 0.f; }
            prev_bi = bi;
        }
        const int jbeg = bj * JT;
        const int jcnt = min(JT, nJ - jbeg);
        __syncthreads();                         // jS reuse + red/acc ordering
        if (tid < jcnt) jS[tid] = jLM[jbeg + tid];
        __syncthreads();
#pragma unroll 4
        for (int k = 0; k < jcnt; ++k) {
            const float2 jv = jS[k];                                  // b64 broadcast
            const float lj = jv.x;
            const int mj = __builtin_amdgcn_readfirstlane(__float_as_int(jv.y));
            // softplus in log2 domain: s = log2(1 + 2^(lj-li)); *ln2 deferred
            const float s0 = __builtin_amdgcn_logf(1.f + __builtin_amdgcn_exp2f(lj - li0));
            const float s1 = __builtin_amdgcn_logf(1.f + __builtin_amdgcn_exp2f(lj - li1));
            Ra0 += s0; Ra1 += s1;
#pragma unroll
            for (int g = 0; g < NG; ++g) {
                const float bg = ((mj >> g) & 1) ? 1.f : 0.f;          // SGPR select
                Rg0[g] = fmaf(bg, s0, Rg0[g]);
                Rg1[g] = fmaf(bg, s1, Rg1[g]);
            }
        }
    }
    if (prev_bi >= 0) flush();
    if (tid < 27) part[tid * NBLK + blk] = acc[tid];   // zeros if no tiles
}

// ---------------------------------------------------------------------------
// Kernel 3: reduce 27 x NBLK partials (scaled by ln2) + double epilogue.
// Counts come straight from the classify kernel's integer counters.
// ---------------------------------------------------------------------------
__global__ __launch_bounds__(512) void k_final(
    const float* __restrict__ part, const int* __restrict__ cnts,
    float* __restrict__ out) {
    __shared__ float fin[27];
    const int tid = threadIdx.x, lane = tid & 63, wave = tid >> 6;
    for (int r = wave; r < 27; r += 8) {
        float s = 0.f;
#pragma unroll
        for (int q = 0; q < NBLK / 64; ++q) s += part[r * NBLK + (q << 6) + lane];
#pragma unroll
        for (int off = 32; off > 0; off >>= 1) s += __shfl_xor(s, off, 64);
        if (lane == 0) fin[r] = s * LN2;     // undo log2-domain accumulation
    }
    __syncthreads();
    if (tid == 0) {
        const long long nT = cnts[0], nN = cnts[1];
        double accd = 0.0; int ngv = 0;
        for (int g = 0; g < NG; ++g) {
            const long long cT = cnts[2 + g], cN = cnts[11 + g];
            const long long c0 = cT * cN;
            const long long c1 = (nT - cT) * cN;
            const long long c2 = cT * (nN - cN);
            const double t0 = (double)fin[g]          / (double)(c0 > 0 ? c0 : 1);
            const double t1 = (double)fin[NG + g]     / (double)(c1 > 0 ? c1 : 1);
            const double t2 = (double)fin[2 * NG + g] / (double)(c2 > 0 ? c2 : 1);
            const int nv = (c0 > 0) + (c1 > 0) + (c2 > 0);
            const double gl = ((c0 > 0 ? t0 : 0.0) + (c1 > 0 ? t1 : 0.0) +
                               (c2 > 0 ? t2 : 0.0)) / (double)(nv > 0 ? nv : 1);
            if (nv > 0) { const double g2 = gl * gl; accd += g2 * g2; ++ngv; }
        }
        const double mp = accd / (double)(ngv > 0 ? ngv : 1);
        const double loss = sqrt(sqrt(mp));  // ^(1/4)
        out[0] = (float)(ngv > 0 ? loss : 0.0);
    }
}

extern "C" void kernel_launch(void* const* d_in, const int* in_sizes, int n_in,
                              void* d_out, int out_size, void* d_ws, size_t ws_size,
                              hipStream_t stream) {
    const float* logits = (const float*)d_in[0];
    const float* ytox   = (const float*)d_in[1];
    const float* yid    = (const float*)d_in[2];
    const int B = in_sizes[0];

    char* ws = (char*)d_ws;
    int*    cnts = (int*)ws;                                  // 20 ints (pad 128B)
    float2* iLM  = (float2*)(ws + 128);                       // B float2
    float2* jLM  = (float2*)(ws + 128 + (size_t)B * 8);       // B float2
    float*  part = (float*)(ws + 128 + (size_t)B * 16);       // 27*NBLK floats

    hipMemsetAsync(cnts, 0, 20 * sizeof(int), stream);
    k_classify<<<dim3((B + 255) / 256), dim3(256), 0, stream>>>(
        logits, ytox, yid, B, cnts, iLM, jLM);
    k_pairs<<<dim3(NBLK), dim3(256), 0, stream>>>(cnts, iLM, jLM, part);
    k_final<<<dim3(1), dim3(512), 0, stream>>>(part, cnts, (float*)d_out);
}